// Round 1
// baseline (7147.567 us; speedup 1.0000x reference)
//
#include <hip/hip_runtime.h>
#include <hip/hip_cooperative_groups.h>

namespace cg = cooperative_groups;

#define NCLS 1000
#define NB 4096
#define PD 512

// ---------------- zero ----------------
__global__ void zero_kernel(float* p, int n) {
  int i = blockIdx.x * 256 + threadIdx.x;
  if (i < n) p[i] = 0.f;
}

// ---------------- generic NT GEMM: C[m][n] = sum_k A[m*K+k]*B[n*K+k] ----------------
// mode 0: write dot. mode 1: write max(rn[m]+cn[n]-2*dot, 0)  (C_weight epilogue)
__global__ void gemm_nt64(const float* __restrict__ A, const float* __restrict__ B,
                          float* __restrict__ C, int M, int N, int K,
                          const float* __restrict__ rn, const float* __restrict__ cn,
                          int mode) {
  __shared__ float As[16][65];
  __shared__ float Bs[16][65];
  int tid = threadIdx.x;
  int tx = tid & 15, ty = tid >> 4;
  int m0 = blockIdx.y * 64, n0 = blockIdx.x * 64;
  float acc[4][4] = {};
  for (int kk = 0; kk < K; kk += 16) {
#pragma unroll
    for (int p = 0; p < 4; ++p) {
      int r = ty + p * 16;
      int m = m0 + r;
      As[tx][r] = (m < M) ? A[(size_t)m * K + kk + tx] : 0.f;
      int n = n0 + r;
      Bs[tx][r] = (n < N) ? B[(size_t)n * K + kk + tx] : 0.f;
    }
    __syncthreads();
#pragma unroll
    for (int k = 0; k < 16; ++k) {
      float a[4], b[4];
#pragma unroll
      for (int i = 0; i < 4; ++i) a[i] = As[k][ty * 4 + i];
#pragma unroll
      for (int j = 0; j < 4; ++j) b[j] = Bs[k][tx * 4 + j];
#pragma unroll
      for (int i = 0; i < 4; ++i)
#pragma unroll
        for (int j = 0; j < 4; ++j) acc[i][j] += a[i] * b[j];
    }
    __syncthreads();
  }
#pragma unroll
  for (int i = 0; i < 4; ++i) {
    int m = m0 + ty * 4 + i;
    if (m >= M) continue;
#pragma unroll
    for (int j = 0; j < 4; ++j) {
      int n = n0 + tx * 4 + j;
      if (n >= N) continue;
      float val;
      if (mode == 1) {
        float d = rn[m] + cn[n] - 2.f * acc[i][j];
        val = fmaxf(d, 0.f);
      } else {
        val = acc[i][j];
      }
      C[(size_t)m * N + n] = val;
    }
  }
}

// ---------------- row norms (sum of squares) ----------------
__global__ void rownorm(const float* __restrict__ X, float* __restrict__ out, int dim) {
  int r = blockIdx.x;
  float s = 0.f;
  for (int c = threadIdx.x; c < dim; c += 256) {
    float v = X[(size_t)r * dim + c];
    s += v * v;
  }
  __shared__ float red[256];
  red[threadIdx.x] = s;
  __syncthreads();
  for (int st = 128; st > 0; st >>= 1) {
    if (threadIdx.x < st) red[threadIdx.x] += red[threadIdx.x + st];
    __syncthreads();
  }
  if (threadIdx.x == 0) out[r] = red[0];
}

// ---------------- class histogram / scan / scatter ----------------
__global__ void hist_kernel(const int* __restrict__ target, int* cnt, int n) {
  int i = blockIdx.x * 256 + threadIdx.x;
  if (i < n) atomicAdd(&cnt[target[i]], 1);
}

__global__ void scan1000(const int* __restrict__ cnt, int* __restrict__ offs) {
  __shared__ int s[1024];
  int t = threadIdx.x;
  s[t] = (t < NCLS) ? cnt[t] : 0;
  __syncthreads();
  for (int d = 1; d < 1024; d <<= 1) {
    int v = (t >= d) ? s[t - d] : 0;
    __syncthreads();
    s[t] += v;
    __syncthreads();
  }
  if (t < NCLS) offs[t] = s[t] - cnt[t];  // exclusive prefix
}

__global__ void scatter_kernel(const int* __restrict__ target, const int* __restrict__ offs,
                               int* fill, int* order, int* clss, int n) {
  int i = blockIdx.x * 256 + threadIdx.x;
  if (i < n) {
    int c = target[i];
    int p = atomicAdd(&fill[c], 1);
    int pos = offs[c] + p;
    order[pos] = i;
    clss[pos] = c;
  }
}

__global__ void gather_norms(const int* __restrict__ order, const float* __restrict__ ftn,
                             const float* __restrict__ fsn, float* ftns, float* fsns, int n) {
  int i = blockIdx.x * 256 + threadIdx.x;
  if (i < n) {
    int r = order[i];
    ftns[i] = ftn[r];
    fsns[i] = fsn[r];
  }
}

// ---------------- within-class pair sums (s_tt, s_ss) ----------------
__global__ void class_pairs(const float* __restrict__ ftp, const float* __restrict__ fsp,
                            const int* __restrict__ order, const int* __restrict__ offs,
                            const int* __restrict__ cnt, const float* __restrict__ ftn,
                            const float* __restrict__ fsn, float* s_tt, float* s_ss) {
  int k = blockIdx.x;
  int c = cnt[k];
  if (c == 0) {
    if (threadIdx.x == 0) { s_tt[k] = 0.f; s_ss[k] = 0.f; }
    return;
  }
  int base = offs[k];
  int lane = threadIdx.x & 63;
  int wave = threadIdx.x >> 6;  // 0..3
  int pairs = c * c;
  float sumt = 0.f, sums = 0.f;
  for (int p = wave; p < pairs; p += 4) {
    int a = p / c, b2 = p - a * c;
    int ia = order[base + a], ib = order[base + b2];
    float dt = 0.f, ds = 0.f;
    for (int e = lane; e < PD; e += 64) {
      dt += ftp[(size_t)ia * PD + e] * ftp[(size_t)ib * PD + e];
      ds += fsp[(size_t)ia * PD + e] * fsp[(size_t)ib * PD + e];
    }
    for (int off = 32; off; off >>= 1) {
      dt += __shfl_down(dt, off);
      ds += __shfl_down(ds, off);
    }
    if (lane == 0) {
      float d1 = fmaxf(ftn[ia] + ftn[ib] - 2.f * dt, 0.f);
      float d2 = fmaxf(fsn[ia] + fsn[ib] - 2.f * ds, 0.f);
      sumt += __expf(-0.5f * d1);
      sums += __expf(-0.5f * d2);
    }
  }
  __shared__ float rt[4], rs[4];
  if (lane == 0) { rt[wave] = sumt; rs[wave] = sums; }
  __syncthreads();
  if (threadIdx.x == 0) {
    s_tt[k] = rt[0] + rt[1] + rt[2] + rt[3];
    s_ss[k] = rs[0] + rs[1] + rs[2] + rs[3];
  }
}

// ---------------- fused Kts GEMM + exp + class-binned reduction ----------------
// rows/cols are class-sorted; 32x32 tile per 256-thread block; per-tile LDS bin table.
__global__ void sts_fused(const float* __restrict__ ftp, const float* __restrict__ fsp,
                          const int* __restrict__ order, const int* __restrict__ clss,
                          const float* __restrict__ ftns, const float* __restrict__ fsns,
                          float* __restrict__ S) {
  __shared__ float As[32][33], Bs[32][33];
  __shared__ float tbl[32][32];
  __shared__ int rslot[32], cslot[32], rcls[32], ccls[32];
  __shared__ int nrs, ncs;
  int tid = threadIdx.x;
  int tx = tid & 15, ty = tid >> 4;
  int i0 = blockIdx.y * 32, j0 = blockIdx.x * 32;

  if (tid == 0) {
    int s = 0, prev = clss[i0];
    rslot[0] = 0; rcls[0] = prev;
    for (int r = 1; r < 32; ++r) {
      int cc = clss[i0 + r];
      if (cc != prev) { ++s; rcls[s] = cc; prev = cc; }
      rslot[r] = s;
    }
    nrs = s + 1;
  } else if (tid == 64) {
    int s = 0, prev = clss[j0];
    cslot[0] = 0; ccls[0] = prev;
    for (int r = 1; r < 32; ++r) {
      int cc = clss[j0 + r];
      if (cc != prev) { ++s; ccls[s] = cc; prev = cc; }
      cslot[r] = s;
    }
    ncs = s + 1;
  }
  for (int t = tid; t < 32 * 32; t += 256) ((float*)tbl)[t] = 0.f;

  float acc00 = 0.f, acc01 = 0.f, acc10 = 0.f, acc11 = 0.f;
  int lr = tid >> 3;            // 0..31
  int lc = (tid & 7) * 4;       // 0,4,..,28
  int rowA = order[i0 + lr];
  int rowB = order[j0 + lr];
  for (int kk = 0; kk < PD; kk += 32) {
    float4 va = *reinterpret_cast<const float4*>(&ftp[(size_t)rowA * PD + kk + lc]);
    float4 vb = *reinterpret_cast<const float4*>(&fsp[(size_t)rowB * PD + kk + lc]);
    As[lc + 0][lr] = va.x; As[lc + 1][lr] = va.y; As[lc + 2][lr] = va.z; As[lc + 3][lr] = va.w;
    Bs[lc + 0][lr] = vb.x; Bs[lc + 1][lr] = vb.y; Bs[lc + 2][lr] = vb.z; Bs[lc + 3][lr] = vb.w;
    __syncthreads();
#pragma unroll
    for (int k = 0; k < 32; ++k) {
      float a0 = As[k][ty], a1 = As[k][ty + 16];
      float b0 = Bs[k][tx], b1 = Bs[k][tx + 16];
      acc00 += a0 * b0; acc01 += a0 * b1;
      acc10 += a1 * b0; acc11 += a1 * b1;
    }
    __syncthreads();
  }
  // accumulate exp values into per-tile class-bin table
  float accs[2][2] = {{acc00, acc01}, {acc10, acc11}};
#pragma unroll
  for (int ii = 0; ii < 2; ++ii) {
#pragma unroll
    for (int jj = 0; jj < 2; ++jj) {
      int il = ty + ii * 16, jl = tx + jj * 16;
      int ig = i0 + il, jg = j0 + jl;
      float d = fmaxf(ftns[ig] + fsns[jg] - 2.f * accs[ii][jj], 0.f);
      float val = __expf(-0.5f * d);
      atomicAdd(&tbl[rslot[il]][cslot[jl]], val);
    }
  }
  __syncthreads();
  int NR = nrs, NC = ncs;
  for (int t = tid; t < NR * NC; t += 256) {
    int r = t / NC, cc = t - r * NC;
    float vsum = tbl[r][cc];
    if (vsum != 0.f) atomicAdd(&S[(size_t)rcls[r] * NCLS + ccls[cc]], vsum);
  }
}

// ---------------- combine: C = C_weight - 0.1*MMD; Km = exp(-10C); KmT ----------------
__global__ void combine(float* __restrict__ C, const float* __restrict__ s_tt,
                        const float* __restrict__ s_ss, const float* __restrict__ S,
                        const int* __restrict__ cnt, float* __restrict__ Km,
                        float* __restrict__ KmT) {
  int idx = blockIdx.x * 256 + threadIdx.x;
  if (idx >= NCLS * NCLS) return;
  int k = idx / NCLS, l = idx - k * NCLS;
  float cw = C[idx];
  int ck = cnt[k], cl = cnt[l];
  float mmd = 0.f;
  if (ck > 0 && cl > 0) {
    float fk = (float)ck, fl = (float)cl;
    mmd = s_tt[k] / (fk * fk) + s_ss[l] / (fl * fl) - 2.f * S[idx] / (fk * fl);
  }
  float c = cw - 0.1f * mmd;
  C[idx] = c;
  float km = __expf(-10.f * c);
  Km[idx] = km;
  KmT[(size_t)l * NCLS + k] = km;
}

// ---------------- cooperative Sinkhorn + final <pi, C> ----------------
__global__ void sinkhorn_kernel(const float* __restrict__ Km, const float* __restrict__ KmT,
                                const float* __restrict__ C, float* __restrict__ u,
                                float* __restrict__ v, float* __restrict__ uprev,
                                int* __restrict__ flag, float* __restrict__ out) {
  cg::grid_group grid = cg::this_grid();
  const int N = NCLS;
  const float ab = 1.f / (float)N;
  int blk = blockIdx.x;                 // 125 blocks
  int lane = threadIdx.x & 63, wave = threadIdx.x >> 6;  // 4 waves
  int gtid = blk * 256 + threadIdx.x;
  if (gtid < N) { u[gtid] = ab; uprev[gtid] = ab; }
  if (gtid == 0) { *flag = 0; out[0] = 0.f; }
  grid.sync();
  int jbase = blk * 8;
  volatile int* vflag = flag;
  for (int it = 0; it < 1000; ++it) {
    // v = b / (K^T u)
#pragma unroll
    for (int q = 0; q < 2; ++q) {
      int j = jbase + wave * 2 + q;
      float s = 0.f;
      for (int i = lane; i < N; i += 64) s += KmT[(size_t)j * N + i] * u[i];
      for (int off = 32; off; off >>= 1) s += __shfl_down(s, off);
      if (lane == 0) v[j] = ab / s;
    }
    grid.sync();
    // u = a / (K v)
#pragma unroll
    for (int q = 0; q < 2; ++q) {
      int i = jbase + wave * 2 + q;
      float s = 0.f;
      for (int j = lane; j < N; j += 64) s += Km[(size_t)i * N + j] * v[j];
      for (int off = 32; off; off >>= 1) s += __shfl_down(s, off);
      if (lane == 0) u[i] = ab / s;
    }
    grid.sync();
    if ((it & 63) == 63 && it < 999) {
      if (blk == 0) {
        float md = 0.f, mu = 0.f;
        for (int i = threadIdx.x; i < N; i += 256) {
          md = fmaxf(md, fabsf(u[i] - uprev[i]));
          mu = fmaxf(mu, fabsf(u[i]));
          uprev[i] = u[i];
        }
        __shared__ float redd[256], redu[256];
        redd[threadIdx.x] = md; redu[threadIdx.x] = mu;
        __syncthreads();
        for (int st = 128; st; st >>= 1) {
          if (threadIdx.x < st) {
            redd[threadIdx.x] = fmaxf(redd[threadIdx.x], redd[threadIdx.x + st]);
            redu[threadIdx.x] = fmaxf(redu[threadIdx.x], redu[threadIdx.x + st]);
          }
          __syncthreads();
        }
        if (threadIdx.x == 0) *flag = (redd[0] < 1e-6f * redu[0]) ? 1 : 0;
      }
      grid.sync();
      if (*vflag) break;
    }
  }
  // out = sum_ij u_i K_ij v_j C_ij
  float part = 0.f;
#pragma unroll
  for (int q = 0; q < 2; ++q) {
    int i = jbase + wave * 2 + q;
    float ui = u[i];
    float s = 0.f;
    for (int j = lane; j < N; j += 64)
      s += Km[(size_t)i * N + j] * v[j] * C[(size_t)i * N + j];
    for (int off = 32; off; off >>= 1) s += __shfl_down(s, off);
    if (lane == 0) part += ui * s;
  }
  if (lane == 0) atomicAdd(out, part);
}

// ---------------- host launch ----------------
extern "C" void kernel_launch(void* const* d_in, const int* in_sizes, int n_in,
                              void* d_out, int out_size, void* d_ws, size_t ws_size,
                              hipStream_t stream) {
  const float* feat_s = (const float*)d_in[0];  // 4096 x 1024
  const float* feat_t = (const float*)d_in[1];  // 4096 x 2048
  const float* w_s = (const float*)d_in[2];     // 1000 x 1024
  const float* w_t = (const float*)d_in[3];     // 1000 x 2048
  const float* Wt = (const float*)d_in[4];      // 512 x 2048
  const float* Ws = (const float*)d_in[5];      // 512 x 1024
  const int* target = (const int*)d_in[6];      // 4096
  float* out = (float*)d_out;

  char* base = (char*)d_ws;
  size_t off = 0;
  auto alloc = [&](size_t bytes) -> void* {
    void* p = base + off;
    off += (bytes + 255) & ~(size_t)255;
    return p;
  };
  float* ftp = (float*)alloc((size_t)NB * PD * 4);
  float* fsp = (float*)alloc((size_t)NB * PD * 4);
  float* wtp = (float*)alloc((size_t)NCLS * PD * 4);
  float* wsp = (float*)alloc((size_t)NCLS * PD * 4);
  float* ftn = (float*)alloc(NB * 4);
  float* fsn = (float*)alloc(NB * 4);
  float* wtn = (float*)alloc(NCLS * 4);
  float* wsn = (float*)alloc(NCLS * 4);
  float* ftns = (float*)alloc(NB * 4);
  float* fsns = (float*)alloc(NB * 4);
  int* cnt = (int*)alloc(NCLS * 4);
  int* offs = (int*)alloc(NCLS * 4);
  int* fill = (int*)alloc(NCLS * 4);
  int* order = (int*)alloc(NB * 4);
  int* clss = (int*)alloc(NB * 4);
  float* s_tt = (float*)alloc(NCLS * 4);
  float* s_ss = (float*)alloc(NCLS * 4);
  float* S = (float*)alloc((size_t)NCLS * NCLS * 4);
  float* Cm = (float*)alloc((size_t)NCLS * NCLS * 4);
  float* Km = (float*)alloc((size_t)NCLS * NCLS * 4);
  float* KmT = (float*)alloc((size_t)NCLS * NCLS * 4);
  float* u = (float*)alloc(1024 * 4);
  float* v = (float*)alloc(1024 * 4);
  float* uprev = (float*)alloc(1024 * 4);
  int* flag = (int*)alloc(256);

  // zeros
  zero_kernel<<<dim3((NCLS * NCLS + 255) / 256), 256, 0, stream>>>(S, NCLS * NCLS);
  zero_kernel<<<dim3(8), 256, 0, stream>>>((float*)cnt, NCLS);
  zero_kernel<<<dim3(8), 256, 0, stream>>>((float*)fill, NCLS);

  // projections: X @ P^T  (NT GEMM, N=512)
  gemm_nt64<<<dim3(PD / 64, (NCLS + 63) / 64), 256, 0, stream>>>(w_t, Wt, wtp, NCLS, PD, 2048, nullptr, nullptr, 0);
  gemm_nt64<<<dim3(PD / 64, (NCLS + 63) / 64), 256, 0, stream>>>(w_s, Ws, wsp, NCLS, PD, 1024, nullptr, nullptr, 0);
  gemm_nt64<<<dim3(PD / 64, NB / 64), 256, 0, stream>>>(feat_t, Wt, ftp, NB, PD, 2048, nullptr, nullptr, 0);
  gemm_nt64<<<dim3(PD / 64, NB / 64), 256, 0, stream>>>(feat_s, Ws, fsp, NB, PD, 1024, nullptr, nullptr, 0);

  // row norms
  rownorm<<<dim3(NCLS), 256, 0, stream>>>(wtp, wtn, PD);
  rownorm<<<dim3(NCLS), 256, 0, stream>>>(wsp, wsn, PD);
  rownorm<<<dim3(NB), 256, 0, stream>>>(ftp, ftn, PD);
  rownorm<<<dim3(NB), 256, 0, stream>>>(fsp, fsn, PD);

  // class grouping
  hist_kernel<<<dim3(NB / 256), 256, 0, stream>>>(target, cnt, NB);
  scan1000<<<dim3(1), 1024, 0, stream>>>(cnt, offs);
  scatter_kernel<<<dim3(NB / 256), 256, 0, stream>>>(target, offs, fill, order, clss, NB);
  gather_norms<<<dim3(NB / 256), 256, 0, stream>>>(order, ftn, fsn, ftns, fsns, NB);

  // within-class pair sums
  class_pairs<<<dim3(NCLS), 256, 0, stream>>>(ftp, fsp, order, offs, cnt, ftn, fsn, s_tt, s_ss);

  // C_weight into Cm
  gemm_nt64<<<dim3((NCLS + 63) / 64, (NCLS + 63) / 64), 256, 0, stream>>>(wtp, wsp, Cm, NCLS, NCLS, PD, wtn, wsn, 1);

  // cross-class kernel sums S_ts
  sts_fused<<<dim3(NB / 32, NB / 32), 256, 0, stream>>>(ftp, fsp, order, clss, ftns, fsns, S);

  // combine into C, Km, KmT
  combine<<<dim3((NCLS * NCLS + 255) / 256), 256, 0, stream>>>(Cm, s_tt, s_ss, S, cnt, Km, KmT);

  // cooperative sinkhorn + final reduction
  {
    const float* KmC = Km; const float* KmTC = KmT; const float* CmC = Cm;
    float* up = u; float* vp = v; float* upr = uprev; int* fl = flag; float* op = out;
    void* args[] = {(void*)&KmC, (void*)&KmTC, (void*)&CmC, (void*)&up,
                    (void*)&vp,  (void*)&upr,  (void*)&fl,  (void*)&op};
    hipLaunchCooperativeKernel((const void*)sinkhorn_kernel, dim3(125), dim3(256), args, 0, stream);
  }
}

// Round 2
// 1841.734 us; speedup vs baseline: 3.8809x; 3.8809x over previous
//
#include <hip/hip_runtime.h>

#define NCLS 1000
#define NB 4096
#define PD 512
#define GBLK 125
#define KSTRIDE 1024

// ---------------- zero ----------------
__global__ void zero_kernel(float* p, int n) {
  int i = blockIdx.x * 256 + threadIdx.x;
  if (i < n) p[i] = 0.f;
}

// ---------------- 128x64 NT GEMM: C[m][n] = sum_k A[m*K+k]*B[n*K+k] ----------------
// mode 0: write dot. mode 1: write max(rn[m]+cn[n]-2*dot, 0)
__global__ __launch_bounds__(256) void gemm_nt128(const float* __restrict__ A,
                          const float* __restrict__ B,
                          float* __restrict__ C, int M, int N, int K,
                          const float* __restrict__ rn, const float* __restrict__ cn,
                          int mode) {
  __shared__ float As[16][132];
  __shared__ float Bs[16][68];
  int tid = threadIdx.x;
  int tx = tid & 15, ty = tid >> 4;
  int sr = tid >> 2;            // 0..63
  int sc = (tid & 3) * 4;       // 0,4,8,12
  int m0 = blockIdx.y * 128, n0 = blockIdx.x * 64;
  float acc[8][4] = {};
  for (int kk = 0; kk < K; kk += 16) {
#pragma unroll
    for (int p = 0; p < 2; ++p) {
      int m = m0 + sr + p * 64;
      float4 va = make_float4(0.f, 0.f, 0.f, 0.f);
      if (m < M) va = *reinterpret_cast<const float4*>(&A[(size_t)m * K + kk + sc]);
      As[sc + 0][sr + p * 64] = va.x; As[sc + 1][sr + p * 64] = va.y;
      As[sc + 2][sr + p * 64] = va.z; As[sc + 3][sr + p * 64] = va.w;
    }
    {
      int n = n0 + sr;
      float4 vb = make_float4(0.f, 0.f, 0.f, 0.f);
      if (n < N) vb = *reinterpret_cast<const float4*>(&B[(size_t)n * K + kk + sc]);
      Bs[sc + 0][sr] = vb.x; Bs[sc + 1][sr] = vb.y;
      Bs[sc + 2][sr] = vb.z; Bs[sc + 3][sr] = vb.w;
    }
    __syncthreads();
#pragma unroll
    for (int k = 0; k < 16; ++k) {
      float a[8], b[4];
      *reinterpret_cast<float4*>(&a[0]) = *reinterpret_cast<float4*>(&As[k][ty * 8]);
      *reinterpret_cast<float4*>(&a[4]) = *reinterpret_cast<float4*>(&As[k][ty * 8 + 4]);
      *reinterpret_cast<float4*>(&b[0]) = *reinterpret_cast<float4*>(&Bs[k][tx * 4]);
#pragma unroll
      for (int i = 0; i < 8; ++i)
#pragma unroll
        for (int j = 0; j < 4; ++j) acc[i][j] += a[i] * b[j];
    }
    __syncthreads();
  }
#pragma unroll
  for (int i = 0; i < 8; ++i) {
    int m = m0 + ty * 8 + i;
    if (m >= M) continue;
#pragma unroll
    for (int j = 0; j < 4; ++j) {
      int n = n0 + tx * 4 + j;
      if (n >= N) continue;
      float val;
      if (mode == 1) {
        float d = rn[m] + cn[n] - 2.f * acc[i][j];
        val = fmaxf(d, 0.f);
      } else {
        val = acc[i][j];
      }
      C[(size_t)m * N + n] = val;
    }
  }
}

// ---------------- row norms ----------------
__global__ void rownorm(const float* __restrict__ X, float* __restrict__ out, int dim) {
  int r = blockIdx.x;
  float s = 0.f;
  for (int c = threadIdx.x; c < dim; c += 256) {
    float v = X[(size_t)r * dim + c];
    s += v * v;
  }
  __shared__ float red[256];
  red[threadIdx.x] = s;
  __syncthreads();
  for (int st = 128; st > 0; st >>= 1) {
    if (threadIdx.x < st) red[threadIdx.x] += red[threadIdx.x + st];
    __syncthreads();
  }
  if (threadIdx.x == 0) out[r] = red[0];
}

// ---------------- class histogram / scan / scatter ----------------
__global__ void hist_kernel(const int* __restrict__ target, int* cnt, int n) {
  int i = blockIdx.x * 256 + threadIdx.x;
  if (i < n) atomicAdd(&cnt[target[i]], 1);
}

__global__ void scan1000(const int* __restrict__ cnt, int* __restrict__ offs) {
  __shared__ int s[1024];
  int t = threadIdx.x;
  s[t] = (t < NCLS) ? cnt[t] : 0;
  __syncthreads();
  for (int d = 1; d < 1024; d <<= 1) {
    int v = (t >= d) ? s[t - d] : 0;
    __syncthreads();
    s[t] += v;
    __syncthreads();
  }
  if (t < NCLS) offs[t] = s[t] - cnt[t];
}

__global__ void scatter_kernel(const int* __restrict__ target, const int* __restrict__ offs,
                               int* fill, int* order, int* clss, int n) {
  int i = blockIdx.x * 256 + threadIdx.x;
  if (i < n) {
    int c = target[i];
    int p = atomicAdd(&fill[c], 1);
    int pos = offs[c] + p;
    order[pos] = i;
    clss[pos] = c;
  }
}

__global__ void gather_norms(const int* __restrict__ order, const float* __restrict__ ftn,
                             const float* __restrict__ fsn, float* ftns, float* fsns, int n) {
  int i = blockIdx.x * 256 + threadIdx.x;
  if (i < n) {
    int r = order[i];
    ftns[i] = ftn[r];
    fsns[i] = fsn[r];
  }
}

// ---------------- within-class pair sums ----------------
__global__ void class_pairs(const float* __restrict__ ftp, const float* __restrict__ fsp,
                            const int* __restrict__ order, const int* __restrict__ offs,
                            const int* __restrict__ cnt, const float* __restrict__ ftn,
                            const float* __restrict__ fsn, float* s_tt, float* s_ss) {
  int k = blockIdx.x;
  int c = cnt[k];
  if (c == 0) {
    if (threadIdx.x == 0) { s_tt[k] = 0.f; s_ss[k] = 0.f; }
    return;
  }
  int base = offs[k];
  int lane = threadIdx.x & 63;
  int wave = threadIdx.x >> 6;
  int pairs = c * c;
  float sumt = 0.f, sums = 0.f;
  for (int p = wave; p < pairs; p += 4) {
    int a = p / c, b2 = p - a * c;
    int ia = order[base + a], ib = order[base + b2];
    float dt = 0.f, ds = 0.f;
    for (int e = lane; e < PD; e += 64) {
      dt += ftp[(size_t)ia * PD + e] * ftp[(size_t)ib * PD + e];
      ds += fsp[(size_t)ia * PD + e] * fsp[(size_t)ib * PD + e];
    }
    for (int off = 32; off; off >>= 1) {
      dt += __shfl_down(dt, off);
      ds += __shfl_down(ds, off);
    }
    if (lane == 0) {
      float d1 = fmaxf(ftn[ia] + ftn[ib] - 2.f * dt, 0.f);
      float d2 = fmaxf(fsn[ia] + fsn[ib] - 2.f * ds, 0.f);
      sumt += __expf(-0.5f * d1);
      sums += __expf(-0.5f * d2);
    }
  }
  __shared__ float rt[4], rs[4];
  if (lane == 0) { rt[wave] = sumt; rs[wave] = sums; }
  __syncthreads();
  if (threadIdx.x == 0) {
    s_tt[k] = rt[0] + rt[1] + rt[2] + rt[3];
    s_ss[k] = rs[0] + rs[1] + rs[2] + rs[3];
  }
}

// ---------------- fused Kts GEMM + exp + class-binned reduction ----------------
__global__ void sts_fused(const float* __restrict__ ftp, const float* __restrict__ fsp,
                          const int* __restrict__ order, const int* __restrict__ clss,
                          const float* __restrict__ ftns, const float* __restrict__ fsns,
                          float* __restrict__ S) {
  __shared__ float As[32][33], Bs[32][33];
  __shared__ float tbl[32][32];
  __shared__ int rslot[32], cslot[32], rcls[32], ccls[32];
  __shared__ int nrs, ncs;
  int tid = threadIdx.x;
  int tx = tid & 15, ty = tid >> 4;
  int i0 = blockIdx.y * 32, j0 = blockIdx.x * 32;

  if (tid == 0) {
    int s = 0, prev = clss[i0];
    rslot[0] = 0; rcls[0] = prev;
    for (int r = 1; r < 32; ++r) {
      int cc = clss[i0 + r];
      if (cc != prev) { ++s; rcls[s] = cc; prev = cc; }
      rslot[r] = s;
    }
    nrs = s + 1;
  } else if (tid == 64) {
    int s = 0, prev = clss[j0];
    cslot[0] = 0; ccls[0] = prev;
    for (int r = 1; r < 32; ++r) {
      int cc = clss[j0 + r];
      if (cc != prev) { ++s; ccls[s] = cc; prev = cc; }
      cslot[r] = s;
    }
    ncs = s + 1;
  }
  for (int t = tid; t < 32 * 32; t += 256) ((float*)tbl)[t] = 0.f;

  float acc00 = 0.f, acc01 = 0.f, acc10 = 0.f, acc11 = 0.f;
  int lr = tid >> 3;
  int lc = (tid & 7) * 4;
  int rowA = order[i0 + lr];
  int rowB = order[j0 + lr];
  for (int kk = 0; kk < PD; kk += 32) {
    float4 va = *reinterpret_cast<const float4*>(&ftp[(size_t)rowA * PD + kk + lc]);
    float4 vb = *reinterpret_cast<const float4*>(&fsp[(size_t)rowB * PD + kk + lc]);
    As[lc + 0][lr] = va.x; As[lc + 1][lr] = va.y; As[lc + 2][lr] = va.z; As[lc + 3][lr] = va.w;
    Bs[lc + 0][lr] = vb.x; Bs[lc + 1][lr] = vb.y; Bs[lc + 2][lr] = vb.z; Bs[lc + 3][lr] = vb.w;
    __syncthreads();
#pragma unroll
    for (int k = 0; k < 32; ++k) {
      float a0 = As[k][ty], a1 = As[k][ty + 16];
      float b0 = Bs[k][tx], b1 = Bs[k][tx + 16];
      acc00 += a0 * b0; acc01 += a0 * b1;
      acc10 += a1 * b0; acc11 += a1 * b1;
    }
    __syncthreads();
  }
  float accs[2][2] = {{acc00, acc01}, {acc10, acc11}};
#pragma unroll
  for (int ii = 0; ii < 2; ++ii) {
#pragma unroll
    for (int jj = 0; jj < 2; ++jj) {
      int il = ty + ii * 16, jl = tx + jj * 16;
      int ig = i0 + il, jg = j0 + jl;
      float d = fmaxf(ftns[ig] + fsns[jg] - 2.f * accs[ii][jj], 0.f);
      float val = __expf(-0.5f * d);
      atomicAdd(&tbl[rslot[il]][cslot[jl]], val);
    }
  }
  __syncthreads();
  int NR = nrs, NC = ncs;
  for (int t = tid; t < NR * NC; t += 256) {
    int r = t / NC, cc = t - r * NC;
    float vsum = tbl[r][cc];
    if (vsum != 0.f) atomicAdd(&S[(size_t)rcls[r] * NCLS + ccls[cc]], vsum);
  }
}

// ---------------- combine: C = C_weight - 0.1*MMD; Km/KmT padded 1024x1024 ----------------
__global__ void combine(float* __restrict__ C, const float* __restrict__ s_tt,
                        const float* __restrict__ s_ss, const float* __restrict__ S,
                        const int* __restrict__ cnt, float* __restrict__ Km,
                        float* __restrict__ KmT) {
  int idx = blockIdx.x * 256 + threadIdx.x;
  if (idx >= KSTRIDE * KSTRIDE) return;
  int k = idx >> 10, l = idx & 1023;
  float val = 0.f;
  if (k < NCLS && l < NCLS) {
    float cw = C[(size_t)k * NCLS + l];
    int ck = cnt[k], cl = cnt[l];
    float mmd = 0.f;
    if (ck > 0 && cl > 0) {
      float fk = (float)ck, fl = (float)cl;
      mmd = s_tt[k] / (fk * fk) + s_ss[l] / (fl * fl) - 2.f * S[(size_t)k * NCLS + l] / (fk * fl);
    }
    float c = cw - 0.1f * mmd;
    C[(size_t)k * NCLS + l] = c;
    val = __expf(-10.f * c);
  }
  Km[(size_t)k * KSTRIDE + l] = val;
  KmT[(size_t)l * KSTRIDE + k] = val;
}

// ---------------- hand-rolled grid barrier ----------------
__device__ __forceinline__ void gbar(int* arr, int* gen, int ph) {
  __syncthreads();  // all waves' stores drained to L2 (vmcnt(0) per wave)
  const int tid = threadIdx.x;
  if (blockIdx.x == 0) {
    if (tid >= 1 && tid < GBLK) {
      while (__hip_atomic_load(&arr[tid], __ATOMIC_RELAXED, __HIP_MEMORY_SCOPE_AGENT) < ph)
        __builtin_amdgcn_s_sleep(1);
    }
    __syncthreads();
    if (tid == 0) {
      __threadfence();  // acquire producers' data (inv) + flush ours (wbl2)
      __hip_atomic_store(gen, ph, __ATOMIC_RELEASE, __HIP_MEMORY_SCOPE_AGENT);
    }
    __syncthreads();
  } else {
    if (tid == 0) {
      __hip_atomic_store(&arr[blockIdx.x], ph, __ATOMIC_RELEASE, __HIP_MEMORY_SCOPE_AGENT);
      while (__hip_atomic_load(gen, __ATOMIC_RELAXED, __HIP_MEMORY_SCOPE_AGENT) < ph)
        __builtin_amdgcn_s_sleep(1);
      __threadfence();  // invalidate stale L1/L2 before block reads shared data
    }
    __syncthreads();
  }
}

// ---------------- persistent Sinkhorn + final <pi, C> ----------------
__global__ __launch_bounds__(256) void sinkhorn2(
    const float* __restrict__ Km, const float* __restrict__ KmT,
    const float* __restrict__ C, float* __restrict__ u, float* __restrict__ v,
    float* __restrict__ uprev, int* __restrict__ arr, int* __restrict__ gen,
    int* __restrict__ flag, float* __restrict__ out) {
  __shared__ float xl[1024];
  __shared__ int bc;
  const int tid = threadIdx.x, bid = blockIdx.x;
  const int lane = tid & 63, wave = tid >> 6;
  const float ab = 1.f / (float)NCLS;

  if (bid == 0) {
    for (int i = tid; i < 1024; i += 256) {
      float val = (i < NCLS) ? ab : 0.f;
      u[i] = val; uprev[i] = val; v[i] = 0.f;
    }
    if (tid == 0) { *flag = 0; out[0] = 0.f; }
  }
  int ph = 0;
  gbar(arr, gen, ++ph);

  const int j0 = bid * 8 + wave * 2;  // this wave's two rows
  float u0r = ab, u1r = ab;

  for (int it = 0; it < 1000; ++it) {
    // ---- stage u; v = ab / (KmT u) ----
    for (int i = tid; i < 1024; i += 256) xl[i] = u[i];
    __syncthreads();
    {
      const float4* r0 = reinterpret_cast<const float4*>(KmT + (size_t)j0 * KSTRIDE);
      const float4* r1 = reinterpret_cast<const float4*>(KmT + (size_t)(j0 + 1) * KSTRIDE);
      const float4* ul = reinterpret_cast<const float4*>(xl);
      float s0 = 0.f, s1 = 0.f;
#pragma unroll
      for (int q = 0; q < 4; ++q) {
        float4 k0 = r0[lane + 64 * q];
        float4 k1 = r1[lane + 64 * q];
        float4 uu = ul[lane + 64 * q];
        s0 += k0.x * uu.x + k0.y * uu.y + k0.z * uu.z + k0.w * uu.w;
        s1 += k1.x * uu.x + k1.y * uu.y + k1.z * uu.z + k1.w * uu.w;
      }
#pragma unroll
      for (int off = 32; off; off >>= 1) {
        s0 += __shfl_down(s0, off);
        s1 += __shfl_down(s1, off);
      }
      if (lane == 0) { v[j0] = ab / s0; v[j0 + 1] = ab / s1; }
    }
    gbar(arr, gen, ++ph);

    // ---- stage v; u = ab / (Km v) ----
    __syncthreads();  // xl reuse safe
    for (int i = tid; i < 1024; i += 256) xl[i] = v[i];
    __syncthreads();
    {
      const float4* r0 = reinterpret_cast<const float4*>(Km + (size_t)j0 * KSTRIDE);
      const float4* r1 = reinterpret_cast<const float4*>(Km + (size_t)(j0 + 1) * KSTRIDE);
      const float4* vl = reinterpret_cast<const float4*>(xl);
      float s0 = 0.f, s1 = 0.f;
#pragma unroll
      for (int q = 0; q < 4; ++q) {
        float4 k0 = r0[lane + 64 * q];
        float4 k1 = r1[lane + 64 * q];
        float4 vv = vl[lane + 64 * q];
        s0 += k0.x * vv.x + k0.y * vv.y + k0.z * vv.z + k0.w * vv.w;
        s1 += k1.x * vv.x + k1.y * vv.y + k1.z * vv.z + k1.w * vv.w;
      }
#pragma unroll
      for (int off = 32; off; off >>= 1) {
        s0 += __shfl_down(s0, off);
        s1 += __shfl_down(s1, off);
      }
      if (lane == 0) { u[j0] = ab / s0; u[j0 + 1] = ab / s1; }
      u0r = __shfl(ab / s0, 0);  // keep own-row u in registers (broadcast to wave)
      u1r = __shfl(ab / s1, 0);
    }

    if ((it & 15) == 15 && it < 999) {
      gbar(arr, gen, ++ph);
      if (bid == 0) {
        float mrel = 0.f;
        for (int i = tid; i < NCLS; i += 256) {
          float un = u[i], up = uprev[i];
          mrel = fmaxf(mrel, fabsf(un - up) / un);
          uprev[i] = un;
        }
        xl[tid] = mrel;
        __syncthreads();
        for (int st = 128; st; st >>= 1) {
          if (tid < st) xl[tid] = fmaxf(xl[tid], xl[tid + st]);
          __syncthreads();
        }
        if (tid == 0) *flag = (xl[0] < 1e-4f) ? 1 : 0;
      }
      gbar(arr, gen, ++ph);
      if (tid == 0) bc = __hip_atomic_load(flag, __ATOMIC_ACQUIRE, __HIP_MEMORY_SCOPE_AGENT);
      __syncthreads();
      if (bc) break;
    } else {
      gbar(arr, gen, ++ph);
    }
  }

  // ---- out = sum_i u_i * sum_j Km[i][j] v_j C[i][j] ----
  __syncthreads();
  for (int i = tid; i < 1024; i += 256) xl[i] = v[i];
  __syncthreads();
  float part = 0.f;
#pragma unroll
  for (int r = 0; r < 2; ++r) {
    int i = j0 + r;
    float s = 0.f;
    for (int j = lane; j < NCLS; j += 64)
      s += Km[(size_t)i * KSTRIDE + j] * xl[j] * C[(size_t)i * NCLS + j];
#pragma unroll
    for (int off = 32; off; off >>= 1) s += __shfl_down(s, off);
    if (lane == 0) part += (r == 0 ? u0r : u1r) * s;
  }
  if (lane == 0) atomicAdd(out, part);
}

// ---------------- host launch ----------------
extern "C" void kernel_launch(void* const* d_in, const int* in_sizes, int n_in,
                              void* d_out, int out_size, void* d_ws, size_t ws_size,
                              hipStream_t stream) {
  const float* feat_s = (const float*)d_in[0];
  const float* feat_t = (const float*)d_in[1];
  const float* w_s = (const float*)d_in[2];
  const float* w_t = (const float*)d_in[3];
  const float* Wt = (const float*)d_in[4];
  const float* Ws = (const float*)d_in[5];
  const int* target = (const int*)d_in[6];
  float* out = (float*)d_out;

  char* base = (char*)d_ws;
  size_t off = 0;
  auto alloc = [&](size_t bytes) -> void* {
    void* p = base + off;
    off += (bytes + 255) & ~(size_t)255;
    return p;
  };
  float* ftp = (float*)alloc((size_t)NB * PD * 4);
  float* fsp = (float*)alloc((size_t)NB * PD * 4);
  float* wtp = (float*)alloc((size_t)NCLS * PD * 4);
  float* wsp = (float*)alloc((size_t)NCLS * PD * 4);
  float* ftn = (float*)alloc(NB * 4);
  float* fsn = (float*)alloc(NB * 4);
  float* wtn = (float*)alloc(NCLS * 4);
  float* wsn = (float*)alloc(NCLS * 4);
  float* ftns = (float*)alloc(NB * 4);
  float* fsns = (float*)alloc(NB * 4);
  int* cnt = (int*)alloc(NCLS * 4);
  int* offs = (int*)alloc(NCLS * 4);
  int* fill = (int*)alloc(NCLS * 4);
  int* order = (int*)alloc(NB * 4);
  int* clss = (int*)alloc(NB * 4);
  float* s_tt = (float*)alloc(NCLS * 4);
  float* s_ss = (float*)alloc(NCLS * 4);
  float* S = (float*)alloc((size_t)NCLS * NCLS * 4);
  float* Cm = (float*)alloc((size_t)NCLS * NCLS * 4);
  float* Km = (float*)alloc((size_t)KSTRIDE * KSTRIDE * 4);
  float* KmT = (float*)alloc((size_t)KSTRIDE * KSTRIDE * 4);
  float* u = (float*)alloc(1024 * 4);
  float* v = (float*)alloc(1024 * 4);
  float* uprev = (float*)alloc(1024 * 4);
  int* ibuf = (int*)alloc(256 * 4);  // arr[0..127], gen at 128, flag at 129
  int* arr = ibuf;
  int* gen = ibuf + 128;
  int* flag = ibuf + 129;

  zero_kernel<<<dim3((NCLS * NCLS + 255) / 256), 256, 0, stream>>>(S, NCLS * NCLS);
  zero_kernel<<<dim3(8), 256, 0, stream>>>((float*)cnt, NCLS);
  zero_kernel<<<dim3(8), 256, 0, stream>>>((float*)fill, NCLS);
  zero_kernel<<<dim3(1), 256, 0, stream>>>((float*)ibuf, 256);

  // projections: X @ P^T
  gemm_nt128<<<dim3(PD / 64, (NCLS + 127) / 128), 256, 0, stream>>>(w_t, Wt, wtp, NCLS, PD, 2048, nullptr, nullptr, 0);
  gemm_nt128<<<dim3(PD / 64, (NCLS + 127) / 128), 256, 0, stream>>>(w_s, Ws, wsp, NCLS, PD, 1024, nullptr, nullptr, 0);
  gemm_nt128<<<dim3(PD / 64, NB / 128), 256, 0, stream>>>(feat_t, Wt, ftp, NB, PD, 2048, nullptr, nullptr, 0);
  gemm_nt128<<<dim3(PD / 64, NB / 128), 256, 0, stream>>>(feat_s, Ws, fsp, NB, PD, 1024, nullptr, nullptr, 0);

  rownorm<<<dim3(NCLS), 256, 0, stream>>>(wtp, wtn, PD);
  rownorm<<<dim3(NCLS), 256, 0, stream>>>(wsp, wsn, PD);
  rownorm<<<dim3(NB), 256, 0, stream>>>(ftp, ftn, PD);
  rownorm<<<dim3(NB), 256, 0, stream>>>(fsp, fsn, PD);

  hist_kernel<<<dim3(NB / 256), 256, 0, stream>>>(target, cnt, NB);
  scan1000<<<dim3(1), 1024, 0, stream>>>(cnt, offs);
  scatter_kernel<<<dim3(NB / 256), 256, 0, stream>>>(target, offs, fill, order, clss, NB);
  gather_norms<<<dim3(NB / 256), 256, 0, stream>>>(order, ftn, fsn, ftns, fsns, NB);

  class_pairs<<<dim3(NCLS), 256, 0, stream>>>(ftp, fsp, order, offs, cnt, ftn, fsn, s_tt, s_ss);

  // C_weight
  gemm_nt128<<<dim3((NCLS + 63) / 64, (NCLS + 127) / 128), 256, 0, stream>>>(wtp, wsp, Cm, NCLS, NCLS, PD, wtn, wsn, 1);

  sts_fused<<<dim3(NB / 32, NB / 32), 256, 0, stream>>>(ftp, fsp, order, clss, ftns, fsns, S);

  combine<<<dim3((KSTRIDE * KSTRIDE + 255) / 256), 256, 0, stream>>>(Cm, s_tt, s_ss, S, cnt, Km, KmT);

  sinkhorn2<<<dim3(GBLK), 256, 0, stream>>>(Km, KmT, Cm, u, v, uprev, arr, gen, flag, out);
}

// Round 3
// 881.989 us; speedup vs baseline: 8.1039x; 2.0882x over previous
//
#include <hip/hip_runtime.h>

#define NCLS 1000
#define NB 4096
#define PD 512
#define GBLK 125
#define KSTRIDE 1024

typedef __attribute__((ext_vector_type(8))) short bf16x8;
typedef __attribute__((ext_vector_type(4))) float f32x4;

__device__ __forceinline__ ushort f2bf(float x) {
  union { float f; unsigned u; } c; c.f = x;
  unsigned r = c.u + 0x7FFFu + ((c.u >> 16) & 1u);
  return (ushort)(r >> 16);
}
__device__ __forceinline__ float bf2f(ushort h) {
  union { unsigned u; float f; } c; c.u = ((unsigned)h) << 16; return c.f;
}

// ---------------- zero ----------------
__global__ void zero_kernel(float* p, int n) {
  int i = blockIdx.x * 256 + threadIdx.x;
  if (i < n) p[i] = 0.f;
}

// ---------------- f32 -> bf16 (hi only) ----------------
__global__ void conv_kernel(const float* __restrict__ X, ushort* __restrict__ hi, int n4) {
  int i = blockIdx.x * 256 + threadIdx.x;
  if (i >= n4) return;
  float4 v = reinterpret_cast<const float4*>(X)[i];
  ushort4 h;
  h.x = f2bf(v.x); h.y = f2bf(v.y); h.z = f2bf(v.z); h.w = f2bf(v.w);
  reinterpret_cast<ushort4*>(hi)[i] = h;
}

// ---------------- f32 -> bf16 hi + lo (Dekker split) ----------------
__global__ void split_kernel(const float* __restrict__ X, ushort* __restrict__ hi,
                             ushort* __restrict__ lo, int n4) {
  int i = blockIdx.x * 256 + threadIdx.x;
  if (i >= n4) return;
  float4 v = reinterpret_cast<const float4*>(X)[i];
  float vv[4] = {v.x, v.y, v.z, v.w};
  ushort h[4], l[4];
#pragma unroll
  for (int j = 0; j < 4; ++j) {
    h[j] = f2bf(vv[j]);
    l[j] = f2bf(vv[j] - bf2f(h[j]));
  }
  ushort4 h4; h4.x = h[0]; h4.y = h[1]; h4.z = h[2]; h4.w = h[3];
  ushort4 l4; l4.x = l[0]; l4.y = l[1]; l4.z = l[2]; l4.w = l[3];
  reinterpret_cast<ushort4*>(hi)[i] = h4;
  reinterpret_cast<ushort4*>(lo)[i] = l4;
}

// ---------------- split-bf16 MFMA NT GEMM (3 mfma per product) ----------------
// C[m][n] = sum_k A[m][k]*B[n][k]; mode 1: C = max(rn[m]+cn[n]-2*dot, 0)
__global__ __launch_bounds__(256) void gemm_split(
    const ushort* __restrict__ Ahi, const ushort* __restrict__ Alo,
    const ushort* __restrict__ Bhi, const ushort* __restrict__ Blo,
    float* __restrict__ C, int M, int N, int K,
    const float* __restrict__ rn, const float* __restrict__ cn, int mode) {
  int tid = threadIdx.x;
  int lane = tid & 63, wv = tid >> 6;
  int wi = wv >> 1, wj = wv & 1;
  int m0 = blockIdx.y * 64, n0 = blockIdx.x * 64;
  int rA = m0 + wi * 32, rB = n0 + wj * 32;
  int lr = lane & 15, lk = (lane >> 4) << 3;
  bf16x8 zb = {0, 0, 0, 0, 0, 0, 0, 0};
  f32x4 z4 = {0.f, 0.f, 0.f, 0.f};
  f32x4 acc[2][2];
#pragma unroll
  for (int i = 0; i < 2; ++i)
#pragma unroll
    for (int j = 0; j < 2; ++j) acc[i][j] = z4;
  for (int kb = 0; kb < K; kb += 32) {
    bf16x8 ah[2], al[2], bh[2], bl[2];
#pragma unroll
    for (int f = 0; f < 2; ++f) {
      int ra = rA + f * 16 + lr;
      if (ra < M) {
        size_t o = (size_t)ra * K + kb + lk;
        ah[f] = *reinterpret_cast<const bf16x8*>(Ahi + o);
        al[f] = *reinterpret_cast<const bf16x8*>(Alo + o);
      } else { ah[f] = zb; al[f] = zb; }
      int rb = rB + f * 16 + lr;
      if (rb < N) {
        size_t o = (size_t)rb * K + kb + lk;
        bh[f] = *reinterpret_cast<const bf16x8*>(Bhi + o);
        bl[f] = *reinterpret_cast<const bf16x8*>(Blo + o);
      } else { bh[f] = zb; bl[f] = zb; }
    }
#pragma unroll
    for (int i = 0; i < 2; ++i)
#pragma unroll
      for (int j = 0; j < 2; ++j) {
        acc[i][j] = __builtin_amdgcn_mfma_f32_16x16x32_bf16(ah[i], bh[j], acc[i][j], 0, 0, 0);
        acc[i][j] = __builtin_amdgcn_mfma_f32_16x16x32_bf16(ah[i], bl[j], acc[i][j], 0, 0, 0);
        acc[i][j] = __builtin_amdgcn_mfma_f32_16x16x32_bf16(al[i], bh[j], acc[i][j], 0, 0, 0);
      }
  }
#pragma unroll
  for (int i = 0; i < 2; ++i)
#pragma unroll
    for (int j = 0; j < 2; ++j)
#pragma unroll
      for (int r = 0; r < 4; ++r) {
        int m = rA + i * 16 + ((lane >> 4) << 2) + r;
        int n = rB + j * 16 + lr;
        if (m < M && n < N) {
          float vv = acc[i][j][r];
          if (mode == 1) vv = fmaxf(rn[m] + cn[n] - 2.f * vv, 0.f);
          C[(size_t)m * N + n] = vv;
        }
      }
}

// ---------------- plain-bf16 MFMA NT GEMM for features; writes sorted bf16 output ----------------
// G[rank[m]][n] = bf16( sum_k A[m][k]*B[n][k] ); N = PD = 512; M,K multiples of 64/32
__global__ __launch_bounds__(256) void gemm_feat(
    const ushort* __restrict__ A, const ushort* __restrict__ B,
    const int* __restrict__ rank, ushort* __restrict__ G, int K) {
  __shared__ int rk[64];
  int tid = threadIdx.x;
  int lane = tid & 63, wv = tid >> 6;
  int wi = wv >> 1, wj = wv & 1;
  int m0 = blockIdx.y * 64, n0 = blockIdx.x * 64;
  if (tid < 64) rk[tid] = rank[m0 + tid];
  int lr = lane & 15, lk = (lane >> 4) << 3;
  const ushort* pa0 = A + (size_t)(m0 + wi * 32 + lr) * K + lk;
  const ushort* pa1 = pa0 + (size_t)16 * K;
  const ushort* pb0 = B + (size_t)(n0 + wj * 32 + lr) * K + lk;
  const ushort* pb1 = pb0 + (size_t)16 * K;
  f32x4 z4 = {0.f, 0.f, 0.f, 0.f};
  f32x4 a00 = z4, a01 = z4, a10 = z4, a11 = z4;
#pragma unroll 2
  for (int kb = 0; kb < K; kb += 32) {
    bf16x8 a0 = *reinterpret_cast<const bf16x8*>(pa0 + kb);
    bf16x8 a1 = *reinterpret_cast<const bf16x8*>(pa1 + kb);
    bf16x8 b0 = *reinterpret_cast<const bf16x8*>(pb0 + kb);
    bf16x8 b1 = *reinterpret_cast<const bf16x8*>(pb1 + kb);
    a00 = __builtin_amdgcn_mfma_f32_16x16x32_bf16(a0, b0, a00, 0, 0, 0);
    a01 = __builtin_amdgcn_mfma_f32_16x16x32_bf16(a0, b1, a01, 0, 0, 0);
    a10 = __builtin_amdgcn_mfma_f32_16x16x32_bf16(a1, b0, a10, 0, 0, 0);
    a11 = __builtin_amdgcn_mfma_f32_16x16x32_bf16(a1, b1, a11, 0, 0, 0);
  }
  __syncthreads();
  f32x4 acc[2][2] = {{a00, a01}, {a10, a11}};
#pragma unroll
  for (int i = 0; i < 2; ++i)
#pragma unroll
    for (int j = 0; j < 2; ++j)
#pragma unroll
      for (int r = 0; r < 4; ++r) {
        int rloc = wi * 32 + i * 16 + ((lane >> 4) << 2) + r;
        int n = n0 + wj * 32 + j * 16 + lr;
        G[(size_t)rk[rloc] * PD + n] = f2bf(acc[i][j][r]);
      }
}

// ---------------- row norms (f32 input) ----------------
__global__ void rownorm(const float* __restrict__ X, float* __restrict__ out, int dim) {
  int r = blockIdx.x;
  float s = 0.f;
  for (int c = threadIdx.x; c < dim; c += 256) {
    float v = X[(size_t)r * dim + c];
    s += v * v;
  }
  __shared__ float red[256];
  red[threadIdx.x] = s;
  __syncthreads();
  for (int st = 128; st > 0; st >>= 1) {
    if (threadIdx.x < st) red[threadIdx.x] += red[threadIdx.x + st];
    __syncthreads();
  }
  if (threadIdx.x == 0) out[r] = red[0];
}

// ---------------- norms of sorted bf16 rows ----------------
__global__ void norms64(const ushort* __restrict__ ftg, const ushort* __restrict__ fsg,
                        float* __restrict__ ftns, float* __restrict__ fsns) {
  int r = blockIdx.x, lane = threadIdx.x;
  const ushort* a = ftg + (size_t)r * PD;
  const ushort* b = fsg + (size_t)r * PD;
  float st = 0.f, ss = 0.f;
  for (int e = lane; e < PD; e += 64) {
    float x = bf2f(a[e]); st += x * x;
    float y = bf2f(b[e]); ss += y * y;
  }
#pragma unroll
  for (int off = 32; off; off >>= 1) { st += __shfl_down(st, off); ss += __shfl_down(ss, off); }
  if (lane == 0) { ftns[r] = st; fsns[r] = ss; }
}

// ---------------- class histogram / scan / scatter ----------------
__global__ void hist_kernel(const int* __restrict__ target, int* cnt, int n) {
  int i = blockIdx.x * 256 + threadIdx.x;
  if (i < n) atomicAdd(&cnt[target[i]], 1);
}

__global__ void scan1000(const int* __restrict__ cnt, int* __restrict__ offs) {
  __shared__ int s[1024];
  int t = threadIdx.x;
  s[t] = (t < NCLS) ? cnt[t] : 0;
  __syncthreads();
  for (int d = 1; d < 1024; d <<= 1) {
    int v = (t >= d) ? s[t - d] : 0;
    __syncthreads();
    s[t] += v;
    __syncthreads();
  }
  if (t < NCLS) offs[t] = s[t] - cnt[t];
}

__global__ void scatter_kernel(const int* __restrict__ target, const int* __restrict__ offs,
                               int* fill, int* rank, int* clss, int n) {
  int i = blockIdx.x * 256 + threadIdx.x;
  if (i < n) {
    int c = target[i];
    int p = atomicAdd(&fill[c], 1);
    int pos = offs[c] + p;
    rank[i] = pos;
    clss[pos] = c;
  }
}

// ---------------- within-class pair sums (sorted bf16; analytic diagonal) ----------------
__global__ void class_pairs2(const ushort* __restrict__ ftg, const ushort* __restrict__ fsg,
                             const int* __restrict__ offs, const int* __restrict__ cnt,
                             float* __restrict__ s_tt, float* __restrict__ s_ss) {
  int k = blockIdx.x;
  int c = cnt[k];
  if (c == 0) {
    if (threadIdx.x == 0) { s_tt[k] = 0.f; s_ss[k] = 0.f; }
    return;
  }
  int base = offs[k];
  int lane = threadIdx.x & 63, wave = threadIdx.x >> 6;
  int tot = c * (c - 1);  // ordered off-diagonal pairs
  float sumt = 0.f, sums = 0.f;
  for (int p = wave; p < tot; p += 4) {
    int i = p / (c - 1), q = p - i * (c - 1);
    int j = q + (q >= i);
    const ushort* ta = ftg + (size_t)(base + i) * PD;
    const ushort* tb = ftg + (size_t)(base + j) * PD;
    const ushort* sa = fsg + (size_t)(base + i) * PD;
    const ushort* sb = fsg + (size_t)(base + j) * PD;
    float dt = 0.f, ds = 0.f;
    for (int e = lane; e < PD; e += 64) {
      float d1 = bf2f(ta[e]) - bf2f(tb[e]); dt += d1 * d1;
      float d2 = bf2f(sa[e]) - bf2f(sb[e]); ds += d2 * d2;
    }
#pragma unroll
    for (int off = 32; off; off >>= 1) { dt += __shfl_down(dt, off); ds += __shfl_down(ds, off); }
    if (lane == 0) { sumt += __expf(-0.5f * dt); sums += __expf(-0.5f * ds); }
  }
  __shared__ float rt[4], rs[4];
  if (lane == 0) { rt[wave] = sumt; rs[wave] = sums; }
  __syncthreads();
  if (threadIdx.x == 0) {
    s_tt[k] = (float)c + rt[0] + rt[1] + rt[2] + rt[3];
    s_ss[k] = (float)c + rs[0] + rs[1] + rs[2] + rs[3];
  }
}

// ---------------- MFMA Kts + exp + class-binned reduction ----------------
__global__ __launch_bounds__(256) void sts_mfma(
    const ushort* __restrict__ ftg, const ushort* __restrict__ fsg,
    const int* __restrict__ clss, const float* __restrict__ ftns,
    const float* __restrict__ fsns, float* __restrict__ S) {
  __shared__ float tbl[64 * 64];
  __shared__ int lclr[64], lclc[64];
  __shared__ int rslot[64], cslot[64], rcls[64], ccls[64];
  __shared__ float rns[64], cns[64];
  __shared__ int nrs_s, ncs_s;
  int tid = threadIdx.x;
  int lane = tid & 63, wv = tid >> 6;
  int wi = wv >> 1, wj = wv & 1;
  int i0 = blockIdx.y * 64, j0 = blockIdx.x * 64;

  if (tid < 64) { lclr[tid] = clss[i0 + tid]; rns[tid] = ftns[i0 + tid]; }
  else if (tid < 128) { int t = tid - 64; lclc[t] = clss[j0 + t]; cns[t] = fsns[j0 + t]; }
  __syncthreads();
  if (tid == 0) {
    int s = 0, prev = lclr[0]; rslot[0] = 0; rcls[0] = prev;
    for (int r = 1; r < 64; ++r) {
      int cc = lclr[r];
      if (cc != prev) { ++s; rcls[s] = cc; prev = cc; }
      rslot[r] = s;
    }
    nrs_s = s + 1;
  } else if (tid == 64) {
    int s = 0, prev = lclc[0]; cslot[0] = 0; ccls[0] = prev;
    for (int r = 1; r < 64; ++r) {
      int cc = lclc[r];
      if (cc != prev) { ++s; ccls[s] = cc; prev = cc; }
      cslot[r] = s;
    }
    ncs_s = s + 1;
  }
  if (tid >= 128) {
    for (int t = tid - 128; t < 64 * 64; t += 128) tbl[t] = 0.f;
  }

  int lr = lane & 15, lk = (lane >> 4) << 3;
  const ushort* pa0 = ftg + (size_t)(i0 + wi * 32 + lr) * PD + lk;
  const ushort* pa1 = pa0 + 16 * PD;
  const ushort* pb0 = fsg + (size_t)(j0 + wj * 32 + lr) * PD + lk;
  const ushort* pb1 = pb0 + 16 * PD;
  f32x4 z4 = {0.f, 0.f, 0.f, 0.f};
  f32x4 a00 = z4, a01 = z4, a10 = z4, a11 = z4;
#pragma unroll 2
  for (int kb = 0; kb < PD; kb += 32) {
    bf16x8 a0 = *reinterpret_cast<const bf16x8*>(pa0 + kb);
    bf16x8 a1 = *reinterpret_cast<const bf16x8*>(pa1 + kb);
    bf16x8 b0 = *reinterpret_cast<const bf16x8*>(pb0 + kb);
    bf16x8 b1 = *reinterpret_cast<const bf16x8*>(pb1 + kb);
    a00 = __builtin_amdgcn_mfma_f32_16x16x32_bf16(a0, b0, a00, 0, 0, 0);
    a01 = __builtin_amdgcn_mfma_f32_16x16x32_bf16(a0, b1, a01, 0, 0, 0);
    a10 = __builtin_amdgcn_mfma_f32_16x16x32_bf16(a1, b0, a10, 0, 0, 0);
    a11 = __builtin_amdgcn_mfma_f32_16x16x32_bf16(a1, b1, a11, 0, 0, 0);
  }
  __syncthreads();  // slots built + tbl zeroed

  f32x4 acc[2][2] = {{a00, a01}, {a10, a11}};
#pragma unroll
  for (int i = 0; i < 2; ++i)
#pragma unroll
    for (int j = 0; j < 2; ++j) {
      int rb = wi * 32 + i * 16 + ((lane >> 4) << 2);
      int cl = wj * 32 + j * 16 + lr;
      int cs = cslot[cl];
      float cnv = cns[cl];
      float run = 0.f;
      int cur = rslot[rb];
#pragma unroll
      for (int r = 0; r < 4; ++r) {
        float d = fmaxf(rns[rb + r] + cnv - 2.f * acc[i][j][r], 0.f);
        float e = __expf(-0.5f * d);
        int s = rslot[rb + r];
        if (s != cur) { atomicAdd(&tbl[cur * 64 + cs], run); run = 0.f; cur = s; }
        run += e;
      }
      atomicAdd(&tbl[cur * 64 + cs], run);
    }
  __syncthreads();
  int NR = nrs_s, NC = ncs_s;
  for (int t = tid; t < NR * NC; t += 256) {
    int r = t / NC, c2 = t - r * NC;
    float vs = tbl[r * 64 + c2];
    if (vs != 0.f) atomicAdd(&S[(size_t)rcls[r] * NCLS + ccls[c2]], vs);
  }
}

// ---------------- combine: C = C_weight - 0.1*MMD; Km/KmT padded 1024x1024 ----------------
__global__ void combine(float* __restrict__ C, const float* __restrict__ s_tt,
                        const float* __restrict__ s_ss, const float* __restrict__ S,
                        const int* __restrict__ cnt, float* __restrict__ Km,
                        float* __restrict__ KmT) {
  int idx = blockIdx.x * 256 + threadIdx.x;
  if (idx >= KSTRIDE * KSTRIDE) return;
  int k = idx >> 10, l = idx & 1023;
  float val = 0.f;
  if (k < NCLS && l < NCLS) {
    float cw = C[(size_t)k * NCLS + l];
    int ck = cnt[k], cl = cnt[l];
    float mmd = 0.f;
    if (ck > 0 && cl > 0) {
      float fk = (float)ck, fl = (float)cl;
      mmd = s_tt[k] / (fk * fk) + s_ss[l] / (fl * fl) - 2.f * S[(size_t)k * NCLS + l] / (fk * fl);
    }
    float c = cw - 0.1f * mmd;
    C[(size_t)k * NCLS + l] = c;
    val = __expf(-10.f * c);
  }
  Km[(size_t)k * KSTRIDE + l] = val;
  KmT[(size_t)l * KSTRIDE + k] = val;
}

// ---------------- hand-rolled grid barrier ----------------
__device__ __forceinline__ void gbar(int* arr, int* gen, int ph) {
  __syncthreads();
  const int tid = threadIdx.x;
  if (blockIdx.x == 0) {
    if (tid >= 1 && tid < GBLK) {
      while (__hip_atomic_load(&arr[tid], __ATOMIC_RELAXED, __HIP_MEMORY_SCOPE_AGENT) < ph)
        __builtin_amdgcn_s_sleep(1);
    }
    __syncthreads();
    if (tid == 0) {
      __threadfence();
      __hip_atomic_store(gen, ph, __ATOMIC_RELEASE, __HIP_MEMORY_SCOPE_AGENT);
    }
    __syncthreads();
  } else {
    if (tid == 0) {
      __hip_atomic_store(&arr[blockIdx.x], ph, __ATOMIC_RELEASE, __HIP_MEMORY_SCOPE_AGENT);
      while (__hip_atomic_load(gen, __ATOMIC_RELAXED, __HIP_MEMORY_SCOPE_AGENT) < ph)
        __builtin_amdgcn_s_sleep(1);
      __threadfence();
    }
    __syncthreads();
  }
}

// ---------------- persistent Sinkhorn + final <pi, C> ----------------
__global__ __launch_bounds__(256) void sinkhorn2(
    const float* __restrict__ Km, const float* __restrict__ KmT,
    const float* __restrict__ C, float* __restrict__ u, float* __restrict__ v,
    float* __restrict__ uprev, int* __restrict__ arr, int* __restrict__ gen,
    int* __restrict__ flag, float* __restrict__ out) {
  __shared__ float xl[1024];
  __shared__ int bc;
  const int tid = threadIdx.x, bid = blockIdx.x;
  const int lane = tid & 63, wave = tid >> 6;
  const float ab = 1.f / (float)NCLS;

  if (bid == 0) {
    for (int i = tid; i < 1024; i += 256) {
      float val = (i < NCLS) ? ab : 0.f;
      u[i] = val; uprev[i] = val; v[i] = 0.f;
    }
    if (tid == 0) { *flag = 0; out[0] = 0.f; }
  }
  int ph = 0;
  gbar(arr, gen, ++ph);

  const int j0 = bid * 8 + wave * 2;
  float u0r = ab, u1r = ab;

  for (int it = 0; it < 1000; ++it) {
    for (int i = tid; i < 1024; i += 256) xl[i] = u[i];
    __syncthreads();
    {
      const float4* r0 = reinterpret_cast<const float4*>(KmT + (size_t)j0 * KSTRIDE);
      const float4* r1 = reinterpret_cast<const float4*>(KmT + (size_t)(j0 + 1) * KSTRIDE);
      const float4* ul = reinterpret_cast<const float4*>(xl);
      float s0 = 0.f, s1 = 0.f;
#pragma unroll
      for (int q = 0; q < 4; ++q) {
        float4 k0 = r0[lane + 64 * q];
        float4 k1 = r1[lane + 64 * q];
        float4 uu = ul[lane + 64 * q];
        s0 += k0.x * uu.x + k0.y * uu.y + k0.z * uu.z + k0.w * uu.w;
        s1 += k1.x * uu.x + k1.y * uu.y + k1.z * uu.z + k1.w * uu.w;
      }
#pragma unroll
      for (int off = 32; off; off >>= 1) {
        s0 += __shfl_down(s0, off);
        s1 += __shfl_down(s1, off);
      }
      if (lane == 0) { v[j0] = ab / s0; v[j0 + 1] = ab / s1; }
    }
    gbar(arr, gen, ++ph);

    __syncthreads();
    for (int i = tid; i < 1024; i += 256) xl[i] = v[i];
    __syncthreads();
    {
      const float4* r0 = reinterpret_cast<const float4*>(Km + (size_t)j0 * KSTRIDE);
      const float4* r1 = reinterpret_cast<const float4*>(Km + (size_t)(j0 + 1) * KSTRIDE);
      const float4* vl = reinterpret_cast<const float4*>(xl);
      float s0 = 0.f, s1 = 0.f;
#pragma unroll
      for (int q = 0; q < 4; ++q) {
        float4 k0 = r0[lane + 64 * q];
        float4 k1 = r1[lane + 64 * q];
        float4 vv = vl[lane + 64 * q];
        s0 += k0.x * vv.x + k0.y * vv.y + k0.z * vv.z + k0.w * vv.w;
        s1 += k1.x * vv.x + k1.y * vv.y + k1.z * vv.z + k1.w * vv.w;
      }
#pragma unroll
      for (int off = 32; off; off >>= 1) {
        s0 += __shfl_down(s0, off);
        s1 += __shfl_down(s1, off);
      }
      if (lane == 0) { u[j0] = ab / s0; u[j0 + 1] = ab / s1; }
      u0r = __shfl(ab / s0, 0);
      u1r = __shfl(ab / s1, 0);
    }

    if ((it & 15) == 15 && it < 999) {
      gbar(arr, gen, ++ph);
      if (bid == 0) {
        float mrel = 0.f;
        for (int i = tid; i < NCLS; i += 256) {
          float un = u[i], up = uprev[i];
          mrel = fmaxf(mrel, fabsf(un - up) / un);
          uprev[i] = un;
        }
        xl[tid] = mrel;
        __syncthreads();
        for (int st = 128; st; st >>= 1) {
          if (tid < st) xl[tid] = fmaxf(xl[tid], xl[tid + st]);
          __syncthreads();
        }
        if (tid == 0) *flag = (xl[0] < 1e-4f) ? 1 : 0;
      }
      gbar(arr, gen, ++ph);
      if (tid == 0) bc = __hip_atomic_load(flag, __ATOMIC_ACQUIRE, __HIP_MEMORY_SCOPE_AGENT);
      __syncthreads();
      if (bc) break;
    } else {
      gbar(arr, gen, ++ph);
    }
  }

  __syncthreads();
  for (int i = tid; i < 1024; i += 256) xl[i] = v[i];
  __syncthreads();
  float part = 0.f;
#pragma unroll
  for (int r = 0; r < 2; ++r) {
    int i = j0 + r;
    float s = 0.f;
    for (int j = lane; j < NCLS; j += 64)
      s += Km[(size_t)i * KSTRIDE + j] * xl[j] * C[(size_t)i * NCLS + j];
#pragma unroll
    for (int off = 32; off; off >>= 1) s += __shfl_down(s, off);
    if (lane == 0) part += (r == 0 ? u0r : u1r) * s;
  }
  if (lane == 0) atomicAdd(out, part);
}

// ---------------- host launch ----------------
extern "C" void kernel_launch(void* const* d_in, const int* in_sizes, int n_in,
                              void* d_out, int out_size, void* d_ws, size_t ws_size,
                              hipStream_t stream) {
  const float* feat_s = (const float*)d_in[0];  // 4096 x 1024
  const float* feat_t = (const float*)d_in[1];  // 4096 x 2048
  const float* w_s = (const float*)d_in[2];     // 1000 x 1024
  const float* w_t = (const float*)d_in[3];     // 1000 x 2048
  const float* Wt = (const float*)d_in[4];      // 512 x 2048
  const float* Ws = (const float*)d_in[5];      // 512 x 1024
  const int* target = (const int*)d_in[6];      // 4096
  float* out = (float*)d_out;

  char* base = (char*)d_ws;
  size_t off = 0;
  auto alloc = [&](size_t bytes) -> void* {
    void* p = base + off;
    off += (bytes + 255) & ~(size_t)255;
    return p;
  };
  ushort* ftb  = (ushort*)alloc((size_t)NB * 2048 * 2);
  ushort* fsb  = (ushort*)alloc((size_t)NB * 1024 * 2);
  ushort* Wthi = (ushort*)alloc((size_t)512 * 2048 * 2);
  ushort* Wtlo = (ushort*)alloc((size_t)512 * 2048 * 2);
  ushort* Wshi = (ushort*)alloc((size_t)512 * 1024 * 2);
  ushort* Wslo = (ushort*)alloc((size_t)512 * 1024 * 2);
  ushort* wthi = (ushort*)alloc((size_t)NCLS * 2048 * 2);
  ushort* wtlo = (ushort*)alloc((size_t)NCLS * 2048 * 2);
  ushort* wshi = (ushort*)alloc((size_t)NCLS * 1024 * 2);
  ushort* wslo = (ushort*)alloc((size_t)NCLS * 1024 * 2);
  float* wtp   = (float*)alloc((size_t)NCLS * PD * 4);
  float* wsp   = (float*)alloc((size_t)NCLS * PD * 4);
  ushort* wtphi = (ushort*)alloc((size_t)NCLS * PD * 2);
  ushort* wtplo = (ushort*)alloc((size_t)NCLS * PD * 2);
  ushort* wsphi = (ushort*)alloc((size_t)NCLS * PD * 2);
  ushort* wsplo = (ushort*)alloc((size_t)NCLS * PD * 2);
  float* wtn   = (float*)alloc(NCLS * 4);
  float* wsn   = (float*)alloc(NCLS * 4);
  ushort* ftg  = (ushort*)alloc((size_t)NB * PD * 2);
  ushort* fsg  = (ushort*)alloc((size_t)NB * PD * 2);
  float* ftns  = (float*)alloc(NB * 4);
  float* fsns  = (float*)alloc(NB * 4);
  int* cnt     = (int*)alloc(NCLS * 4);
  int* offs    = (int*)alloc(NCLS * 4);
  int* fill    = (int*)alloc(NCLS * 4);
  int* rank    = (int*)alloc(NB * 4);
  int* clss    = (int*)alloc(NB * 4);
  float* s_tt  = (float*)alloc(NCLS * 4);
  float* s_ss  = (float*)alloc(NCLS * 4);
  float* S     = (float*)alloc((size_t)NCLS * NCLS * 4);
  float* Cm    = (float*)alloc((size_t)NCLS * NCLS * 4);
  float* Km    = (float*)alloc((size_t)KSTRIDE * KSTRIDE * 4);
  float* KmT   = (float*)alloc((size_t)KSTRIDE * KSTRIDE * 4);
  float* u     = (float*)alloc(1024 * 4);
  float* v     = (float*)alloc(1024 * 4);
  float* uprev = (float*)alloc(1024 * 4);
  int* ibuf    = (int*)alloc(256 * 4);
  int* arr = ibuf;
  int* gen = ibuf + 128;
  int* flag = ibuf + 129;

  // zeros
  zero_kernel<<<dim3((NCLS * NCLS + 255) / 256), 256, 0, stream>>>(S, NCLS * NCLS);
  zero_kernel<<<dim3(8), 256, 0, stream>>>((float*)cnt, NCLS);
  zero_kernel<<<dim3(8), 256, 0, stream>>>((float*)fill, NCLS);
  zero_kernel<<<dim3(1), 256, 0, stream>>>((float*)ibuf, 256);

  // class grouping (needed by gemm_feat epilogue)
  hist_kernel<<<dim3(NB / 256), 256, 0, stream>>>(target, cnt, NB);
  scan1000<<<dim3(1), 1024, 0, stream>>>(cnt, offs);
  scatter_kernel<<<dim3(NB / 256), 256, 0, stream>>>(target, offs, fill, rank, clss, NB);

  // conversions
  conv_kernel<<<dim3(NB * 2048 / 4 / 256), 256, 0, stream>>>(feat_t, ftb, NB * 2048 / 4);
  conv_kernel<<<dim3(NB * 1024 / 4 / 256), 256, 0, stream>>>(feat_s, fsb, NB * 1024 / 4);
  split_kernel<<<dim3(512 * 2048 / 4 / 256), 256, 0, stream>>>(Wt, Wthi, Wtlo, 512 * 2048 / 4);
  split_kernel<<<dim3(512 * 1024 / 4 / 256), 256, 0, stream>>>(Ws, Wshi, Wslo, 512 * 1024 / 4);
  split_kernel<<<dim3((NCLS * 2048 / 4 + 255) / 256), 256, 0, stream>>>(w_t, wthi, wtlo, NCLS * 2048 / 4);
  split_kernel<<<dim3((NCLS * 1024 / 4 + 255) / 256), 256, 0, stream>>>(w_s, wshi, wslo, NCLS * 1024 / 4);

  // weight projections (split precision): wtp = w_t @ Wt^T, wsp = w_s @ Ws^T
  gemm_split<<<dim3(PD / 64, (NCLS + 63) / 64), 256, 0, stream>>>(wthi, wtlo, Wthi, Wtlo, wtp, NCLS, PD, 2048, nullptr, nullptr, 0);
  gemm_split<<<dim3(PD / 64, (NCLS + 63) / 64), 256, 0, stream>>>(wshi, wslo, Wshi, Wslo, wsp, NCLS, PD, 1024, nullptr, nullptr, 0);

  rownorm<<<dim3(NCLS), 256, 0, stream>>>(wtp, wtn, PD);
  rownorm<<<dim3(NCLS), 256, 0, stream>>>(wsp, wsn, PD);

  split_kernel<<<dim3((NCLS * PD / 4 + 255) / 256), 256, 0, stream>>>(wtp, wtphi, wtplo, NCLS * PD / 4);
  split_kernel<<<dim3((NCLS * PD / 4 + 255) / 256), 256, 0, stream>>>(wsp, wsphi, wsplo, NCLS * PD / 4);

  // C_weight = max(||wtp_k||^2 + ||wsp_l||^2 - 2 wtp.wsp, 0)
  gemm_split<<<dim3((NCLS + 63) / 64, (NCLS + 63) / 64), 256, 0, stream>>>(wtphi, wtplo, wsphi, wsplo, Cm, NCLS, NCLS, PD, wtn, wsn, 1);

  // feature projections (bf16), written sorted
  gemm_feat<<<dim3(PD / 64, NB / 64), 256, 0, stream>>>(ftb, Wthi, rank, ftg, 2048);
  gemm_feat<<<dim3(PD / 64, NB / 64), 256, 0, stream>>>(fsb, Wshi, rank, fsg, 1024);

  norms64<<<dim3(NB), 64, 0, stream>>>(ftg, fsg, ftns, fsns);

  class_pairs2<<<dim3(NCLS), 256, 0, stream>>>(ftg, fsg, offs, cnt, s_tt, s_ss);

  sts_mfma<<<dim3(NB / 64, NB / 64), 256, 0, stream>>>(ftg, fsg, clss, ftns, fsns, S);

  combine<<<dim3((KSTRIDE * KSTRIDE + 255) / 256), 256, 0, stream>>>(Cm, s_tt, s_ss, S, cnt, Km, KmT);

  sinkhorn2<<<dim3(GBLK), 256, 0, stream>>>(Km, KmT, Cm, u, v, uprev, arr, gen, flag, out);
}